// Round 11
// baseline (845.732 us; speedup 1.0000x reference)
//
#include <hip/hip_runtime.h>
#include <hip/hip_bf16.h>
#include <stdint.h>

using short8 = __attribute__((ext_vector_type(8))) short;
using f32x16 = __attribute__((ext_vector_type(16))) float;

#define DD 1152
#define ROW 6912   // QKV row stride (elements)

static __device__ __forceinline__ float bf2f(uint32_t h){
  union { uint32_t u; float f; } v; v.u = (h & 0xffffu) << 16; return v.f;
}
static __device__ __forceinline__ ushort f2bf(float f){
  union { float f; uint32_t u; } v; v.f = f;
  uint32_t r = (v.u + 0x7fffu + ((v.u >> 16) & 1u)) >> 16;
  return (ushort)r;
}
static __device__ __forceinline__ uint32_t pack2(float a, float b){
  return (uint32_t)f2bf(a) | ((uint32_t)f2bf(b) << 16);
}

static __device__ __forceinline__ void gload16(const void* g, void* l){
  __builtin_amdgcn_global_load_lds(
      (const __attribute__((address_space(1))) void*)g,
      (__attribute__((address_space(3))) void*)l, 16, 0, 0);
}

// ====== 256x128 NT GEMM, BK=32, 8 waves (4Mx2N, 64x64/wave), 5-buffer pipeline ======
// ============ barrier per 2 iters + reg-dbuf frags + 32x32x16 MFMA ================
// C[m][n] = alpha * sum_k A[m][k]*B[n][k], optional batch via blockIdx.y (strides).
//
// Base = R7 (best measured: 770 us total; PV 192 us, MfmaUtil 35.7, 0 conflicts).
// R11 change: 16x16x32 -> 32x32x16 MFMA (ubench 2382 vs 2075 TF; 8 MFMA/tile/thread
// instead of 16 for identical FLOPs — less matrix-pipe time + issue pressure).
// Per-wave 64x64 = 2x2 frags of 32x32, K-step 16 x2 per BK=32 tile. Same LDS bytes,
// same 8 ds_read_b128/thread/tile, same swizzle ((row>>1)&3 invariant under +32).
// C/D map (m74/m101-verified): col=lane&31, row=(reg&3)+8*(reg>>2)+4*(lane>>5).
//
// Pipeline (R7, proven): 5 LDS buffers (60 KiB), stage depth 4, ONE barrier per
// 2-iter window; waves drift within a window so ds_read bursts overlap MFMA bursts
// across waves (m114). Races: stage at iter u targets buf (u-1)%5, last prefetch-
// read at iter u-2 (earlier window, >=1 barrier). Landing: window-end vmcnt(3)
// keeps only the odd-iter stage in flight; tail drains to 0. Prime-vs-stage race
// closed by the extra post-prime barrier.
// LDS swizzle: stored colq q at row r holds source colq q^((r>>1)&3); staged via
// inverse-swizzled global source + linear gload_lds dest (rule 21; 0 conflicts
// measured R3-R10).
// TAG: distinct symbol per call-site. EPI: 0 = bf16 store; 2 = split@1152 + bias.
template<int EPI, int TAG>
__global__ __launch_bounds__(512, 2)
void gemmRP(const ushort* __restrict__ A, int lda, long long sA,
            const ushort* __restrict__ Bm, int ldb, long long sB,
            void* __restrict__ Cout, int ldc, long long sC,
            int K, float alpha, int ntx, int row0,
            float* __restrict__ out0, float* __restrict__ out1,
            const float* __restrict__ bias0, const float* __restrict__ bias1)
{
  __shared__ __align__(16) ushort lds[61440];   // 5 x 12288 elems = 60 KiB... (x2B = 120 KiB)
  const int tid  = threadIdx.x;
  const int w    = tid >> 6, lane = tid & 63;
  const int wr   = w >> 1, wc = w & 1;          // 4(M) x 2(N)

  A  += (long long)blockIdx.y * sA;
  Bm += (long long)blockIdx.y * sB;

  // T1: bijective XCD swizzle (all grids divisible by 8)
  const int nwg = gridDim.x;
  const int wg  = blockIdx.x;
  const int swz = (wg & 7) * (nwg >> 3) + (wg >> 3);
  const int tx = swz % ntx, ty = swz / ntx;
  const int m0 = ty * 256, n0 = tx * 128;

  // ---- staging: A segs 0..15 (16 rows x 32 cols), wave w stages segs 2w,2w+1;
  //      B segs 0..7, wave w stages seg w. lane l -> in-seg row l>>2, stored colq l&3,
  //      inverse-swizzled source colq (l&3)^((l>>3)&3).
  const int srow = lane >> 2;
  const int scol = 8 * ((lane & 3) ^ ((lane >> 3) & 3));
  const ushort* gA0 = A  + (size_t)(m0 + (2 * w) * 16 + srow) * lda + scol;
  const ushort* gA1 = gA0 + (size_t)16 * lda;
  const ushort* gB0 = Bm + (size_t)(n0 + w * 16 + srow) * ldb + scol;

  auto stage = [&](int t, int bf) {
    ushort* Lb = lds + bf * 12288;
    gload16(gA0 + t * 32, Lb + (2 * w) * 512);
    gload16(gA1 + t * 32, Lb + (2 * w) * 512 + 512);
    gload16(gB0 + t * 32, Lb + 8192 + w * 512);
  };

  // ---- 32x32x16 fragment ds_read addresses (elems), col XOR-swizzled per row
  // frag (mf): rows wr*64 + mf*32 + (lane&31); k = ks*16 + (lane>>5)*8 + 0..7
  // colq = ks*2 + (lane>>5), swizzled ^ ((row>>1)&3) (invariant under +32).
  const int l31 = lane & 31, hi = lane >> 5;
  const int rA = wr * 64 + l31;
  const int rB = wc * 64 + l31;
  const int sAx = (rA >> 1) & 3;
  const int sBx = (rB >> 1) & 3;
  const int adA00 = rA * 32        + 8 * ((0 + hi) ^ sAx);  // mf0 ks0
  const int adA01 = rA * 32        + 8 * ((2 + hi) ^ sAx);  // mf0 ks1
  const int adA10 = (rA + 32) * 32 + 8 * ((0 + hi) ^ sAx);  // mf1 ks0
  const int adA11 = (rA + 32) * 32 + 8 * ((2 + hi) ^ sAx);  // mf1 ks1
  const int adB00 = 8192 + rB * 32        + 8 * ((0 + hi) ^ sBx);
  const int adB01 = 8192 + rB * 32        + 8 * ((2 + hi) ^ sBx);
  const int adB10 = 8192 + (rB + 32) * 32 + 8 * ((0 + hi) ^ sBx);
  const int adB11 = 8192 + (rB + 32) * 32 + 8 * ((2 + hi) ^ sBx);

  f32x16 acc[2][2];
#pragma unroll
  for (int m = 0; m < 2; m++)
#pragma unroll
    for (int n = 0; n < 2; n++)
      acc[m][n] = f32x16{0.f,0.f,0.f,0.f,0.f,0.f,0.f,0.f,
                         0.f,0.f,0.f,0.f,0.f,0.f,0.f,0.f};

  const int nt = K >> 5;   // K in {1152,2304,4096} -> nt in {36,72,128}, all even

  short8 aP[2][2], bP[2][2], aQ[2][2], bQ[2][2];   // [mf|nf][ks]

  auto rdA = [&](const ushort* Lb, short8 (&a)[2][2]) {
    a[0][0] = *(const short8*)(Lb + adA00);
    a[0][1] = *(const short8*)(Lb + adA01);
    a[1][0] = *(const short8*)(Lb + adA10);
    a[1][1] = *(const short8*)(Lb + adA11);
  };
  auto rdB = [&](const ushort* Lb, short8 (&b)[2][2]) {
    b[0][0] = *(const short8*)(Lb + adB00);
    b[0][1] = *(const short8*)(Lb + adB01);
    b[1][0] = *(const short8*)(Lb + adB10);
    b[1][1] = *(const short8*)(Lb + adB11);
  };

  // prologue: 4 tiles staged; vmcnt(3) => bufs 0,1,2 landed; prime P from buf0;
  // extra barrier closes prime-read(buf0) vs iter-1 stage(5 -> buf0) race.
  stage(0, 0); stage(1, 1); stage(2, 2); stage(3, 3);
  asm volatile("s_waitcnt vmcnt(3)" ::: "memory");
  __builtin_amdgcn_s_barrier();
  rdA(lds, aP); rdB(lds, bP);
  __builtin_amdgcn_s_barrier();

  int b1 = 1;   // buffer holding tile t+1 (prefetch source)
  int b4 = 4;   // stage target: buffer for tile t+4

  for (int t = 0; t < nt; t += 2) {
    // ---- even iter t: MFMA on P; prefetch tile t+1 -> Q; stage tile t+4
    if (t + 1 < nt) {
      const ushort* Lb = lds + b1 * 12288;
      rdA(Lb, aQ); rdB(Lb, bQ);
    }
    if (t + 4 < nt) stage(t + 4, b4);
    __builtin_amdgcn_s_setprio(1);
#pragma unroll
    for (int ks = 0; ks < 2; ks++)
#pragma unroll
      for (int m = 0; m < 2; m++)
#pragma unroll
        for (int n = 0; n < 2; n++)
          acc[m][n] = __builtin_amdgcn_mfma_f32_32x32x16_bf16(aP[m][ks], bP[n][ks], acc[m][n], 0, 0, 0);
    __builtin_amdgcn_s_setprio(0);
    b1++; if (b1 == 5) b1 = 0;
    b4++; if (b4 == 5) b4 = 0;

    // ---- odd iter t+1: MFMA on Q; prefetch tile t+2 -> P; stage tile t+5
    if (t + 2 < nt) {
      const ushort* Lb = lds + b1 * 12288;
      rdA(Lb, aP); rdB(Lb, bP);
    }
    if (t + 5 < nt) stage(t + 5, b4);
    __builtin_amdgcn_s_setprio(1);
#pragma unroll
    for (int ks = 0; ks < 2; ks++)
#pragma unroll
      for (int m = 0; m < 2; m++)
#pragma unroll
        for (int n = 0; n < 2; n++)
          acc[m][n] = __builtin_amdgcn_mfma_f32_32x32x16_bf16(aQ[m][ks], bQ[n][ks], acc[m][n], 0, 0, 0);
    __builtin_amdgcn_s_setprio(0);
    b1++; if (b1 == 5) b1 = 0;
    b4++; if (b4 == 5) b4 = 0;

    // ---- window end: keep only the odd-iter stage in flight (3 loads); tail -> 0
    if (t + 5 < nt) asm volatile("s_waitcnt vmcnt(3)" ::: "memory");
    else            asm volatile("s_waitcnt vmcnt(0)" ::: "memory");
    __builtin_amdgcn_s_barrier();
  }

  // ---- epilogue: 32x32 C/D map col=lane&31, row=(reg&3)+8*(reg>>2)+4*hi (m74/m101)
#pragma unroll
  for (int m = 0; m < 2; m++) {
#pragma unroll
    for (int n = 0; n < 2; n++) {
      const int colb = n0 + wc * 64 + n * 32 + l31;
#pragma unroll
      for (int r = 0; r < 16; r++) {
        const int row = m0 + wr * 64 + m * 32 + (r & 3) + 8 * (r >> 2) + 4 * hi;
        float val = acc[m][n][r] * alpha;
        if (EPI == 0) {
          ((ushort*)Cout)[(long long)blockIdx.y * sC + (size_t)row * ldc + colb] = f2bf(val);
        } else {
          const int orow = row0 + row;
          if (colb < DD) out0[(size_t)orow * DD + colb] = val + bias0[colb];
          else           out1[(size_t)orow * DD + (colb - DD)] = val + bias1[colb - DD];
        }
      }
    }
  }
}

// ---------------- fp32 -> bf16 conversion ----------------
__global__ __launch_bounds__(256)
void cvt_f32_bf16(const float* __restrict__ src, ushort* __restrict__ dst, int n4)
{
  int stride = gridDim.x * blockDim.x;
  for (int i = blockIdx.x * blockDim.x + threadIdx.x; i < n4; i += stride) {
    float4 v = ((const float4*)src)[i];
    uint2 o;
    o.x = pack2(v.x, v.y);
    o.y = pack2(v.z, v.w);
    ((uint2*)dst)[i] = o;
  }
}

// ---------------- in-place RMS norm on Q/K segments of QKV rows ----------------
__global__ __launch_bounds__(256)
void rms_inplace(ushort* __restrict__ qkv,
                 const float* __restrict__ sq_text, const float* __restrict__ sq_pix,
                 const float* __restrict__ sk_text, const float* __restrict__ sk_pix)
{
  const int row = blockIdx.x;
  const int tid = threadIdx.x, wave = tid >> 6, lane = tid & 63;
  ushort* seg = qkv + (size_t)row * ROW + wave * 1152;
  const float* scale = (wave == 0) ? sq_text : (wave == 1) ? sq_pix
                     : (wave == 2) ? sk_text : sk_pix;
  float ss = 0.f;
  for (int g = lane; g < 144; g += 64) {
    uint4 p = *(const uint4*)(seg + g * 8);
    float f0 = bf2f(p.x), f1 = bf2f(p.x >> 16), f2 = bf2f(p.y), f3 = bf2f(p.y >> 16);
    float f4 = bf2f(p.z), f5 = bf2f(p.z >> 16), f6 = bf2f(p.w), f7 = bf2f(p.w >> 16);
    ss += f0*f0 + f1*f1 + f2*f2 + f3*f3 + f4*f4 + f5*f5 + f6*f6 + f7*f7;
  }
#pragma unroll
  for (int off = 32; off; off >>= 1) ss += __shfl_xor(ss, off);
  float rms = sqrtf(ss) * 0.0294627825f;  // 1/sqrt(1152)
  float inv = 1.0f / (rms + 1e-8f);
  for (int g = lane; g < 144; g += 64) {
    int d0 = g * 8;
    uint4 p = *(const uint4*)(seg + d0);
    float f[8];
    f[0]=bf2f(p.x); f[1]=bf2f(p.x>>16); f[2]=bf2f(p.y); f[3]=bf2f(p.y>>16);
    f[4]=bf2f(p.z); f[5]=bf2f(p.z>>16); f[6]=bf2f(p.w); f[7]=bf2f(p.w>>16);
    uint4 o;
    o.x = pack2(f[0]*scale[d0+0]*inv, f[1]*scale[d0+1]*inv);
    o.y = pack2(f[2]*scale[d0+2]*inv, f[3]*scale[d0+3]*inv);
    o.z = pack2(f[4]*scale[d0+4]*inv, f[5]*scale[d0+5]*inv);
    o.w = pack2(f[6]*scale[d0+6]*inv, f[7]*scale[d0+7]*inv);
    *(uint4*)(seg + d0) = o;
  }
}

// ---------------- V transpose: Vt[b][d][n] = V[b][n][d] ----------------
__global__ __launch_bounds__(256)
void transpose_v(const ushort* __restrict__ qkv, ushort* __restrict__ Vt)
{
  __shared__ ushort t[64][72];
  const int nb = blockIdx.x, db = blockIdx.y, b = blockIdx.z;
  const int tid = threadIdx.x;
  const int d0 = db * 64;
  const int srccol = 4608 + d0;
  const int rr = tid >> 3, cc = (tid & 7) * 8;
#pragma unroll
  for (int it = 0; it < 2; it++) {
    int r = rr + it * 32;
    uint4 p = *(const uint4*)(qkv + (size_t)(b * 4096 + nb * 64 + r) * ROW + srccol + cc);
    *(uint4*)&t[r][cc] = p;
  }
  __syncthreads();
#pragma unroll
  for (int it = 0; it < 2; it++) {
    int d = rr + it * 32;
    uint4 o;
    o.x = (uint32_t)t[cc+0][d] | ((uint32_t)t[cc+1][d] << 16);
    o.y = (uint32_t)t[cc+2][d] | ((uint32_t)t[cc+3][d] << 16);
    o.z = (uint32_t)t[cc+4][d] | ((uint32_t)t[cc+5][d] << 16);
    o.w = (uint32_t)t[cc+6][d] | ((uint32_t)t[cc+7][d] << 16);
    *(uint4*)(Vt + ((size_t)b * 2304 + d0 + d) * 4096 + nb * 64 + cc) = o;
  }
}

// ---------------- row softmax on bf16 S (4096 wide), in place ----------------
__global__ __launch_bounds__(256)
void softmax_bf16(ushort* __restrict__ S)
{
  const int row = blockIdx.x;
  ushort* sr = S + (size_t)row * 4096;
  const int tid = threadIdx.x, wave = tid >> 6, lane = tid & 63;
  __shared__ float red[8];
  uint4 p0 = ((const uint4*)sr)[tid * 2];
  uint4 p1 = ((const uint4*)sr)[tid * 2 + 1];
  float f[16];
  f[0]=bf2f(p0.x); f[1]=bf2f(p0.x>>16); f[2]=bf2f(p0.y); f[3]=bf2f(p0.y>>16);
  f[4]=bf2f(p0.z); f[5]=bf2f(p0.z>>16); f[6]=bf2f(p0.w); f[7]=bf2f(p0.w>>16);
  f[8]=bf2f(p1.x); f[9]=bf2f(p1.x>>16); f[10]=bf2f(p1.y); f[11]=bf2f(p1.y>>16);
  f[12]=bf2f(p1.z); f[13]=bf2f(p1.z>>16); f[14]=bf2f(p1.w); f[15]=bf2f(p1.w>>16);
  float mx = f[0];
#pragma unroll
  for (int j = 1; j < 16; j++) mx = fmaxf(mx, f[j]);
#pragma unroll
  for (int off = 32; off; off >>= 1) mx = fmaxf(mx, __shfl_xor(mx, off));
  if (lane == 0) red[wave] = mx;
  __syncthreads();
  mx = fmaxf(fmaxf(red[0], red[1]), fmaxf(red[2], red[3]));
  float s = 0.f;
#pragma unroll
  for (int j = 0; j < 16; j++) { f[j] = expf(f[j] - mx); s += f[j]; }
#pragma unroll
  for (int off = 32; off; off >>= 1) s += __shfl_xor(s, off);
  if (lane == 0) red[4 + wave] = s;
  __syncthreads();
  s = red[4] + red[5] + red[6] + red[7];
  float inv = 1.0f / s;
  uint4 o0, o1;
  o0.x = pack2(f[0]*inv, f[1]*inv);  o0.y = pack2(f[2]*inv, f[3]*inv);
  o0.z = pack2(f[4]*inv, f[5]*inv);  o0.w = pack2(f[6]*inv, f[7]*inv);
  o1.x = pack2(f[8]*inv, f[9]*inv);  o1.y = pack2(f[10]*inv, f[11]*inv);
  o1.z = pack2(f[12]*inv, f[13]*inv); o1.w = pack2(f[14]*inv, f[15]*inv);
  ((uint4*)sr)[tid * 2]     = o0;
  ((uint4*)sr)[tid * 2 + 1] = o1;
}

// ---------------- host launch ----------------
extern "C" void kernel_launch(void* const* d_in, const int* in_sizes, int n_in,
                              void* d_out, int out_size, void* d_ws, size_t ws_size,
                              hipStream_t stream)
{
  const float* x          = (const float*)d_in[0];
  const float* Wqkv_pix   = (const float*)d_in[2];
  const float* Wqkv_text  = (const float*)d_in[3];
  const float* sq_text    = (const float*)d_in[4];
  const float* sk_text    = (const float*)d_in[5];
  const float* sq_pix     = (const float*)d_in[6];
  const float* sk_pix     = (const float*)d_in[7];
  const float* Wproj_pix  = (const float*)d_in[8];
  const float* bproj_pix  = (const float*)d_in[9];
  const float* Wproj_text = (const float*)d_in[10];
  const float* bproj_text = (const float*)d_in[11];

  // workspace layout (bytes), ws <= 195,166,208:
  //  QKV [0, 113,246,208)  8192x6912 bf16 [q_text q_pix k_text k_pix v_text v_pix]
  //    after QK(b0): batch-0 half [0, 56,623,104) dead ->
  //      S1 [0, 33,554,432)           (written by QK(b1); QK(b1) reads bytes >= 56.6M)
  //      Z  [33,554,432, 71,303,168)  (written by PV after all of QKV is dead)
  //  Vt  [113,246,208, 150,994,944)   2x 2304x4096 bf16  (xb aliased, dead pre-transpose)
  //  S0  [150,994,944, 184,549,376)   4096x4096 bf16     (Wb aliased, dead pre-QK(b0))
  //  Wpb [184,549,376, 195,166,208)   2304x2304 bf16
  if (ws_size < 195166208ULL) return;
  char* ws = (char*)d_ws;
  ushort* QKV = (ushort*)(ws);
  ushort* S1  = (ushort*)(ws);
  ushort* Z   = (ushort*)(ws + 33554432);
  ushort* Vt  = (ushort*)(ws + 113246208);
  ushort* S0  = (ushort*)(ws + 150994944);
  ushort* Wpb = (ushort*)(ws + 184549376);
  ushort* xb  = (ushort*)(ws + 113246208);   // alias
  ushort* Wb  = (ushort*)(ws + 150994944);   // alias

  // conversions; Wb packed row-blocks: [q_text q_pix k_text k_pix v_text v_pix]
  cvt_f32_bf16<<<2048, 256, 0, stream>>>(x, xb, 9437184 / 4);
  for (int t = 0; t < 3; t++) {
    cvt_f32_bf16<<<512, 256, 0, stream>>>(Wqkv_text + (size_t)t * 1327104,
                                          Wb + (size_t)(2 * t) * 1327104, 1327104 / 4);
    cvt_f32_bf16<<<512, 256, 0, stream>>>(Wqkv_pix + (size_t)t * 1327104,
                                          Wb + (size_t)(2 * t + 1) * 1327104, 1327104 / 4);
  }
  cvt_f32_bf16<<<512, 256, 0, stream>>>(Wproj_pix, Wpb, 2654208 / 4);
  cvt_f32_bf16<<<512, 256, 0, stream>>>(Wproj_text, Wpb + 2654208, 2654208 / 4);

  // G1: QKV = xb @ Wb^T   (8192 x 6912, K=1152) — 32x54 = 1728 WGs
  gemmRP<0, 1><<<dim3(1728), 512, 0, stream>>>(xb, 1152, 0, Wb, 1152, 0, QKV, ROW, 0,
                                               1152, 1.0f, 54, 0,
                                               nullptr, nullptr, nullptr, nullptr);
  rms_inplace<<<8192, 256, 0, stream>>>(QKV, sq_text, sq_pix, sk_text, sk_pix);
  {
    dim3 g(64, 36, 2);
    transpose_v<<<g, 256, 0, stream>>>(QKV, Vt);
  }

  const float scale = 1.0f / 48.0f;  // (2*1152)^-0.5
  const size_t slab = (size_t)4096 * ROW;

  // QK b0: S0 = scale * Q0 @ K0^T  (4096x4096, K=2304) — 16x32 = 512 WGs
  gemmRP<0, 2><<<dim3(512), 512, 0, stream>>>(QKV, ROW, 0, QKV + 2304, ROW, 0,
                                              S0, 4096, 0, 2304, scale, 32, 0,
                                              nullptr, nullptr, nullptr, nullptr);
  softmax_bf16<<<4096, 256, 0, stream>>>(S0);
  // QK b1: S1 = scale * Q1 @ K1^T   (batch-0 QKV region now dead)
  gemmRP<0, 2><<<dim3(512), 512, 0, stream>>>(QKV + slab, ROW, 0, QKV + slab + 2304, ROW, 0,
                                              S1, 4096, 0, 2304, scale, 32, 0,
                                              nullptr, nullptr, nullptr, nullptr);
  softmax_bf16<<<4096, 256, 0, stream>>>(S1);

  // PV combined (both batches): Z = P @ V  (4096x2304, K=4096) — (16x18, 2) = 576 WGs
  {
    long long sAb = (long long)(S1 - S0);            // negative stride, intentional
    long long sBb = (long long)2304 * 4096;
    long long sCb = (long long)4096 * 2304;
    gemmRP<0, 3><<<dim3(288, 2), 512, 0, stream>>>(S0, 4096, sAb, Vt, 4096, sBb,
                                                   Z, 2304, sCb, 4096, 1.0f, 18, 0,
                                                   nullptr, nullptr, nullptr, nullptr);
  }

  // proj: out = Z @ Wp^T (8192 x 2304, K=2304), split at col 1152 + bias — 32x18=576 WGs
  {
    float* out0 = (float*)d_out;
    float* out1 = out0 + 9437184;
    gemmRP<2, 4><<<dim3(576), 512, 0, stream>>>(Z, 2304, 0, Wpb, 2304, 0, nullptr, 0, 0,
                                                2304, 1.0f, 18, 0,
                                                out0, out1, bproj_pix, bproj_text);
  }
}

// Round 12
// 765.453 us; speedup vs baseline: 1.1049x; 1.1049x over previous
//
#include <hip/hip_runtime.h>
#include <hip/hip_bf16.h>
#include <stdint.h>

using short8 = __attribute__((ext_vector_type(8))) short;
using f32x4  = __attribute__((ext_vector_type(4))) float;

#define DD 1152
#define ROW 6912   // QKV row stride (elements)

static __device__ __forceinline__ float bf2f(uint32_t h){
  union { uint32_t u; float f; } v; v.u = (h & 0xffffu) << 16; return v.f;
}
static __device__ __forceinline__ ushort f2bf(float f){
  union { float f; uint32_t u; } v; v.f = f;
  uint32_t r = (v.u + 0x7fffu + ((v.u >> 16) & 1u)) >> 16;
  return (ushort)r;
}
static __device__ __forceinline__ uint32_t pack2(float a, float b){
  return (uint32_t)f2bf(a) | ((uint32_t)f2bf(b) << 16);
}

static __device__ __forceinline__ void gload16(const void* g, void* l){
  __builtin_amdgcn_global_load_lds(
      (const __attribute__((address_space(1))) void*)g,
      (__attribute__((address_space(3))) void*)l, 16, 0, 0);
}

// ====== 256x128 NT GEMM, BK=32, 8 waves (4Mx2N, 64x64/wave), 5-buffer pipeline ======
// ============= barrier per 2 iters (wave-drift window) + reg-dbuf frags =============
// C[m][n] = alpha * sum_k A[m][k]*B[n][k], optional batch via blockIdx.y (strides).
//
// This is the best-measured configuration of the session (R7: 770 us total, PV 192 us,
// MfmaUtil 35.7, 0 bank conflicts). R11's 32x32-MFMA variant regressed (1.9e7 bank
// conflicts: rows r,r+8,r+16,r+24 alias under the period-8 XOR swizzle when a wave
// reads 32 distinct rows). 16x16x32 frag reads (two half-waves on the SAME 16 rows,
// colq differing by 2) are conflict-free with this swizzle — keep them.
//
// Race derivation (holds for any intra-window drift; barriers bound drift):
//  W-A-R: stage at iter u targets buf (u+4)%5 == (u-1)%5, last prefetch-READ at iter
//    u-2 — always in an earlier 2-iter window => >=1 barrier between read and write.
//    Prime-read of buf0 vs stage(5->buf0) at iter 1: closed by a barrier after prime.
//  Landing (R-A-W): window-end vmcnt(3) => only the odd-iter stage (3 loads) stays
//    in flight; everything the next window reads has landed. Tail drains to 0.
// LDS swizzle: stored colq q at row r holds source colq q^((r>>1)&3); staged via
//  inverse-swizzled global source + linear gload_lds dest (rule 21; 0 conflicts
//  measured R3-R10).
// TAG: distinct symbol per call-site. EPI: 0 = bf16 store; 2 = split@1152 + bias.
template<int EPI, int TAG>
__global__ __launch_bounds__(512, 2)
void gemmRP(const ushort* __restrict__ A, int lda, long long sA,
            const ushort* __restrict__ Bm, int ldb, long long sB,
            void* __restrict__ Cout, int ldc, long long sC,
            int K, float alpha, int ntx, int row0,
            float* __restrict__ out0, float* __restrict__ out1,
            const float* __restrict__ bias0, const float* __restrict__ bias1)
{
  __shared__ __align__(16) ushort lds[61440];   // 5 x 12288 elems = 120 KiB
  const int tid  = threadIdx.x;
  const int w    = tid >> 6, lane = tid & 63;
  const int wr   = w >> 1, wc = w & 1;          // 4(M) x 2(N)

  A  += (long long)blockIdx.y * sA;
  Bm += (long long)blockIdx.y * sB;

  // T1: bijective XCD swizzle (all grids divisible by 8)
  const int nwg = gridDim.x;
  const int wg  = blockIdx.x;
  const int swz = (wg & 7) * (nwg >> 3) + (wg >> 3);
  const int tx = swz % ntx, ty = swz / ntx;
  const int m0 = ty * 256, n0 = tx * 128;

  // ---- staging: A segs 0..15 (16 rows x 32 cols), wave w stages segs 2w,2w+1;
  //      B segs 0..7, wave w stages seg w. lane l -> in-seg row l>>2, stored colq l&3,
  //      inverse-swizzled source colq (l&3)^((l>>3)&3).
  const int srow = lane >> 2;
  const int scol = 8 * ((lane & 3) ^ ((lane >> 3) & 3));
  const ushort* gA0 = A  + (size_t)(m0 + (2 * w) * 16 + srow) * lda + scol;
  const ushort* gA1 = gA0 + (size_t)16 * lda;
  const ushort* gB0 = Bm + (size_t)(n0 + w * 16 + srow) * ldb + scol;

  auto stage = [&](int t, int bf) {
    ushort* Lb = lds + bf * 12288;
    gload16(gA0 + t * 32, Lb + (2 * w) * 512);
    gload16(gA1 + t * 32, Lb + (2 * w) * 512 + 512);
    gload16(gB0 + t * 32, Lb + 8192 + w * 512);
  };

  // ---- ds_read fragment addresses (elems), col XOR-swizzled per row
  const int kq   = lane >> 4;
  const int rowA = wr * 64 + (lane & 15);     // (row>>1)&3 invariant under +16*m
  const int adA  = rowA * 32 + 8 * (kq ^ ((rowA >> 1) & 3));
  const int rowB = wc * 64 + (lane & 15);
  const int adB  = 8192 + rowB * 32 + 8 * (kq ^ ((rowB >> 1) & 3));

  f32x4 acc[4][4];
#pragma unroll
  for (int m = 0; m < 4; m++)
#pragma unroll
    for (int n = 0; n < 4; n++) acc[m][n] = f32x4{0.f, 0.f, 0.f, 0.f};

  const int nt = K >> 5;   // K in {1152,2304,4096} -> nt in {36,72,128}, all even

  short8 aP[4], bP[4], aQ[4], bQ[4];

  // prologue: 4 tiles staged; vmcnt(3) => bufs 0,1,2 landed; prime P from buf0;
  // extra barrier closes prime-read(buf0) vs iter-1 stage(5 -> buf0) race.
  stage(0, 0); stage(1, 1); stage(2, 2); stage(3, 3);
  asm volatile("s_waitcnt vmcnt(3)" ::: "memory");
  __builtin_amdgcn_s_barrier();
#pragma unroll
  for (int m = 0; m < 4; m++) aP[m] = *(const short8*)(lds + adA + m * 512);
#pragma unroll
  for (int n = 0; n < 4; n++) bP[n] = *(const short8*)(lds + adB + n * 512);
  __builtin_amdgcn_s_barrier();

  int b1 = 1;   // buffer holding tile t+1 (prefetch source)
  int b4 = 4;   // stage target: buffer for tile t+4

  for (int t = 0; t < nt; t += 2) {
    // ---- even iter t: MFMA on P; prefetch tile t+1 -> Q; stage tile t+4
    if (t + 1 < nt) {
      const ushort* Lb = lds + b1 * 12288;
#pragma unroll
      for (int m = 0; m < 4; m++) aQ[m] = *(const short8*)(Lb + adA + m * 512);
#pragma unroll
      for (int n = 0; n < 4; n++) bQ[n] = *(const short8*)(Lb + adB + n * 512);
    }
    if (t + 4 < nt) stage(t + 4, b4);
    __builtin_amdgcn_s_setprio(1);
#pragma unroll
    for (int m = 0; m < 4; m++)
#pragma unroll
      for (int n = 0; n < 4; n++)
        acc[m][n] = __builtin_amdgcn_mfma_f32_16x16x32_bf16(aP[m], bP[n], acc[m][n], 0, 0, 0);
    __builtin_amdgcn_s_setprio(0);
    b1++; if (b1 == 5) b1 = 0;
    b4++; if (b4 == 5) b4 = 0;

    // ---- odd iter t+1: MFMA on Q; prefetch tile t+2 -> P; stage tile t+5
    if (t + 2 < nt) {
      const ushort* Lb = lds + b1 * 12288;
#pragma unroll
      for (int m = 0; m < 4; m++) aP[m] = *(const short8*)(Lb + adA + m * 512);
#pragma unroll
      for (int n = 0; n < 4; n++) bP[n] = *(const short8*)(Lb + adB + n * 512);
    }
    if (t + 5 < nt) stage(t + 5, b4);
    __builtin_amdgcn_s_setprio(1);
#pragma unroll
    for (int m = 0; m < 4; m++)
#pragma unroll
      for (int n = 0; n < 4; n++)
        acc[m][n] = __builtin_amdgcn_mfma_f32_16x16x32_bf16(aQ[m], bQ[n], acc[m][n], 0, 0, 0);
    __builtin_amdgcn_s_setprio(0);
    b1++; if (b1 == 5) b1 = 0;
    b4++; if (b4 == 5) b4 = 0;

    // ---- window end: keep only the odd-iter stage in flight (3 loads); tail -> 0
    if (t + 5 < nt) asm volatile("s_waitcnt vmcnt(3)" ::: "memory");
    else            asm volatile("s_waitcnt vmcnt(0)" ::: "memory");
    __builtin_amdgcn_s_barrier();
  }

  // ---- epilogue: C frag mapping col=lane&15, row=(lane>>4)*4+v (m89-verified)
#pragma unroll
  for (int m = 0; m < 4; m++) {
#pragma unroll
    for (int v = 0; v < 4; v++) {
      const int row = m0 + wr * 64 + m * 16 + (lane >> 4) * 4 + v;
#pragma unroll
      for (int n = 0; n < 4; n++) {
        const int col = n0 + wc * 64 + n * 16 + (lane & 15);
        float val = acc[m][n][v] * alpha;
        if (EPI == 0) {
          ((ushort*)Cout)[(long long)blockIdx.y * sC + (size_t)row * ldc + col] = f2bf(val);
        } else {
          const int orow = row0 + row;
          if (col < DD) out0[(size_t)orow * DD + col] = val + bias0[col];
          else          out1[(size_t)orow * DD + (col - DD)] = val + bias1[col - DD];
        }
      }
    }
  }
}

// ---------------- fp32 -> bf16 conversion ----------------
__global__ __launch_bounds__(256)
void cvt_f32_bf16(const float* __restrict__ src, ushort* __restrict__ dst, int n4)
{
  int stride = gridDim.x * blockDim.x;
  for (int i = blockIdx.x * blockDim.x + threadIdx.x; i < n4; i += stride) {
    float4 v = ((const float4*)src)[i];
    uint2 o;
    o.x = pack2(v.x, v.y);
    o.y = pack2(v.z, v.w);
    ((uint2*)dst)[i] = o;
  }
}

// ---------------- in-place RMS norm on Q/K segments of QKV rows ----------------
__global__ __launch_bounds__(256)
void rms_inplace(ushort* __restrict__ qkv,
                 const float* __restrict__ sq_text, const float* __restrict__ sq_pix,
                 const float* __restrict__ sk_text, const float* __restrict__ sk_pix)
{
  const int row = blockIdx.x;
  const int tid = threadIdx.x, wave = tid >> 6, lane = tid & 63;
  ushort* seg = qkv + (size_t)row * ROW + wave * 1152;
  const float* scale = (wave == 0) ? sq_text : (wave == 1) ? sq_pix
                     : (wave == 2) ? sk_text : sk_pix;
  float ss = 0.f;
  for (int g = lane; g < 144; g += 64) {
    uint4 p = *(const uint4*)(seg + g * 8);
    float f0 = bf2f(p.x), f1 = bf2f(p.x >> 16), f2 = bf2f(p.y), f3 = bf2f(p.y >> 16);
    float f4 = bf2f(p.z), f5 = bf2f(p.z >> 16), f6 = bf2f(p.w), f7 = bf2f(p.w >> 16);
    ss += f0*f0 + f1*f1 + f2*f2 + f3*f3 + f4*f4 + f5*f5 + f6*f6 + f7*f7;
  }
#pragma unroll
  for (int off = 32; off; off >>= 1) ss += __shfl_xor(ss, off);
  float rms = sqrtf(ss) * 0.0294627825f;  // 1/sqrt(1152)
  float inv = 1.0f / (rms + 1e-8f);
  for (int g = lane; g < 144; g += 64) {
    int d0 = g * 8;
    uint4 p = *(const uint4*)(seg + d0);
    float f[8];
    f[0]=bf2f(p.x); f[1]=bf2f(p.x>>16); f[2]=bf2f(p.y); f[3]=bf2f(p.y>>16);
    f[4]=bf2f(p.z); f[5]=bf2f(p.z>>16); f[6]=bf2f(p.w); f[7]=bf2f(p.w>>16);
    uint4 o;
    o.x = pack2(f[0]*scale[d0+0]*inv, f[1]*scale[d0+1]*inv);
    o.y = pack2(f[2]*scale[d0+2]*inv, f[3]*scale[d0+3]*inv);
    o.z = pack2(f[4]*scale[d0+4]*inv, f[5]*scale[d0+5]*inv);
    o.w = pack2(f[6]*scale[d0+6]*inv, f[7]*scale[d0+7]*inv);
    *(uint4*)(seg + d0) = o;
  }
}

// ---------------- V transpose: Vt[b][d][n] = V[b][n][d] ----------------
__global__ __launch_bounds__(256)
void transpose_v(const ushort* __restrict__ qkv, ushort* __restrict__ Vt)
{
  __shared__ ushort t[64][72];
  const int nb = blockIdx.x, db = blockIdx.y, b = blockIdx.z;
  const int tid = threadIdx.x;
  const int d0 = db * 64;
  const int srccol = 4608 + d0;
  const int rr = tid >> 3, cc = (tid & 7) * 8;
#pragma unroll
  for (int it = 0; it < 2; it++) {
    int r = rr + it * 32;
    uint4 p = *(const uint4*)(qkv + (size_t)(b * 4096 + nb * 64 + r) * ROW + srccol + cc);
    *(uint4*)&t[r][cc] = p;
  }
  __syncthreads();
#pragma unroll
  for (int it = 0; it < 2; it++) {
    int d = rr + it * 32;
    uint4 o;
    o.x = (uint32_t)t[cc+0][d] | ((uint32_t)t[cc+1][d] << 16);
    o.y = (uint32_t)t[cc+2][d] | ((uint32_t)t[cc+3][d] << 16);
    o.z = (uint32_t)t[cc+4][d] | ((uint32_t)t[cc+5][d] << 16);
    o.w = (uint32_t)t[cc+6][d] | ((uint32_t)t[cc+7][d] << 16);
    *(uint4*)(Vt + ((size_t)b * 2304 + d0 + d) * 4096 + nb * 64 + cc) = o;
  }
}

// ------- row softmax on bf16 S (4096 wide), in place; both batches in one launch ------
__global__ __launch_bounds__(256)
void softmax_bf16(ushort* __restrict__ S0, ushort* __restrict__ S1)
{
  const int row = blockIdx.x;
  ushort* sr = (row < 4096) ? (S0 + (size_t)row * 4096)
                            : (S1 + (size_t)(row - 4096) * 4096);
  const int tid = threadIdx.x, wave = tid >> 6, lane = tid & 63;
  __shared__ float red[8];
  uint4 p0 = ((const uint4*)sr)[tid * 2];
  uint4 p1 = ((const uint4*)sr)[tid * 2 + 1];
  float f[16];
  f[0]=bf2f(p0.x); f[1]=bf2f(p0.x>>16); f[2]=bf2f(p0.y); f[3]=bf2f(p0.y>>16);
  f[4]=bf2f(p0.z); f[5]=bf2f(p0.z>>16); f[6]=bf2f(p0.w); f[7]=bf2f(p0.w>>16);
  f[8]=bf2f(p1.x); f[9]=bf2f(p1.x>>16); f[10]=bf2f(p1.y); f[11]=bf2f(p1.y>>16);
  f[12]=bf2f(p1.z); f[13]=bf2f(p1.z>>16); f[14]=bf2f(p1.w); f[15]=bf2f(p1.w>>16);
  float mx = f[0];
#pragma unroll
  for (int j = 1; j < 16; j++) mx = fmaxf(mx, f[j]);
#pragma unroll
  for (int off = 32; off; off >>= 1) mx = fmaxf(mx, __shfl_xor(mx, off));
  if (lane == 0) red[wave] = mx;
  __syncthreads();
  mx = fmaxf(fmaxf(red[0], red[1]), fmaxf(red[2], red[3]));
  float s = 0.f;
#pragma unroll
  for (int j = 0; j < 16; j++) { f[j] = expf(f[j] - mx); s += f[j]; }
#pragma unroll
  for (int off = 32; off; off >>= 1) s += __shfl_xor(s, off);
  if (lane == 0) red[4 + wave] = s;
  __syncthreads();
  s = red[4] + red[5] + red[6] + red[7];
  float inv = 1.0f / s;
  uint4 o0, o1;
  o0.x = pack2(f[0]*inv, f[1]*inv);  o0.y = pack2(f[2]*inv, f[3]*inv);
  o0.z = pack2(f[4]*inv, f[5]*inv);  o0.w = pack2(f[6]*inv, f[7]*inv);
  o1.x = pack2(f[8]*inv, f[9]*inv);  o1.y = pack2(f[10]*inv, f[11]*inv);
  o1.z = pack2(f[12]*inv, f[13]*inv); o1.w = pack2(f[14]*inv, f[15]*inv);
  ((uint4*)sr)[tid * 2]     = o0;
  ((uint4*)sr)[tid * 2 + 1] = o1;
}

// ---------------- host launch ----------------
extern "C" void kernel_launch(void* const* d_in, const int* in_sizes, int n_in,
                              void* d_out, int out_size, void* d_ws, size_t ws_size,
                              hipStream_t stream)
{
  const float* x          = (const float*)d_in[0];
  const float* Wqkv_pix   = (const float*)d_in[2];
  const float* Wqkv_text  = (const float*)d_in[3];
  const float* sq_text    = (const float*)d_in[4];
  const float* sk_text    = (const float*)d_in[5];
  const float* sq_pix     = (const float*)d_in[6];
  const float* sk_pix     = (const float*)d_in[7];
  const float* Wproj_pix  = (const float*)d_in[8];
  const float* bproj_pix  = (const float*)d_in[9];
  const float* Wproj_text = (const float*)d_in[10];
  const float* bproj_text = (const float*)d_in[11];

  // workspace layout (bytes), ws <= 195,166,208:
  //  QKV [0, 113,246,208)  8192x6912 bf16 [q_text q_pix k_text k_pix v_text v_pix]
  //    after QK(b0): batch-0 half [0, 56,623,104) dead ->
  //      S1 [0, 33,554,432)           (written by QK(b1); QK(b1) reads bytes >= 56.6M)
  //      Z  [33,554,432, 71,303,168)  (written by PV after all of QKV is dead)
  //  Vt  [113,246,208, 150,994,944)   2x 2304x4096 bf16  (xb aliased, dead pre-transpose)
  //  S0  [150,994,944, 184,549,376)   4096x4096 bf16     (Wb aliased, dead pre-QK(b0))
  //  Wpb [184,549,376, 195,166,208)   2304x2304 bf16
  if (ws_size < 195166208ULL) return;
  char* ws = (char*)d_ws;
  ushort* QKV = (ushort*)(ws);
  ushort* S1  = (ushort*)(ws);
  ushort* Z   = (ushort*)(ws + 33554432);
  ushort* Vt  = (ushort*)(ws + 113246208);
  ushort* S0  = (ushort*)(ws + 150994944);
  ushort* Wpb = (ushort*)(ws + 184549376);
  ushort* xb  = (ushort*)(ws + 113246208);   // alias
  ushort* Wb  = (ushort*)(ws + 150994944);   // alias

  // conversions; Wb packed row-blocks: [q_text q_pix k_text k_pix v_text v_pix]
  cvt_f32_bf16<<<2048, 256, 0, stream>>>(x, xb, 9437184 / 4);
  for (int t = 0; t < 3; t++) {
    cvt_f32_bf16<<<512, 256, 0, stream>>>(Wqkv_text + (size_t)t * 1327104,
                                          Wb + (size_t)(2 * t) * 1327104, 1327104 / 4);
    cvt_f32_bf16<<<512, 256, 0, stream>>>(Wqkv_pix + (size_t)t * 1327104,
                                          Wb + (size_t)(2 * t + 1) * 1327104, 1327104 / 4);
  }
  cvt_f32_bf16<<<512, 256, 0, stream>>>(Wproj_pix, Wpb, 2654208 / 4);
  cvt_f32_bf16<<<512, 256, 0, stream>>>(Wproj_text, Wpb + 2654208, 2654208 / 4);

  // G1: QKV = xb @ Wb^T   (8192 x 6912, K=1152) — 32x54 = 1728 WGs
  gemmRP<0, 1><<<dim3(1728), 512, 0, stream>>>(xb, 1152, 0, Wb, 1152, 0, QKV, ROW, 0,
                                               1152, 1.0f, 54, 0,
                                               nullptr, nullptr, nullptr, nullptr);
  rms_inplace<<<8192, 256, 0, stream>>>(QKV, sq_text, sq_pix, sk_text, sk_pix);
  {
    dim3 g(64, 36, 2);
    transpose_v<<<g, 256, 0, stream>>>(QKV, Vt);
  }

  const float scale = 1.0f / 48.0f;  // (2*1152)^-0.5
  const size_t slab = (size_t)4096 * ROW;

  // QK b0: S0 = scale * Q0 @ K0^T  (4096x4096, K=2304) — 16x32 = 512 WGs
  gemmRP<0, 2><<<dim3(512), 512, 0, stream>>>(QKV, ROW, 0, QKV + 2304, ROW, 0,
                                              S0, 4096, 0, 2304, scale, 32, 0,
                                              nullptr, nullptr, nullptr, nullptr);
  // QK b1: S1 = scale * Q1 @ K1^T   (batch-0 QKV region dead after QK b0)
  gemmRP<0, 2><<<dim3(512), 512, 0, stream>>>(QKV + slab, ROW, 0, QKV + slab + 2304, ROW, 0,
                                              S1, 4096, 0, 2304, scale, 32, 0,
                                              nullptr, nullptr, nullptr, nullptr);
  // softmax, both batches in one launch
  softmax_bf16<<<8192, 256, 0, stream>>>(S0, S1);

  // PV combined (both batches): Z = P @ V  (4096x2304, K=4096) — (16x18, 2) = 576 WGs
  {
    long long sAb = (long long)(S1 - S0);            // negative stride, intentional
    long long sBb = (long long)2304 * 4096;
    long long sCb = (long long)4096 * 2304;
    gemmRP<0, 3><<<dim3(288, 2), 512, 0, stream>>>(S0, 4096, sAb, Vt, 4096, sBb,
                                                   Z, 2304, sCb, 4096, 1.0f, 18, 0,
                                                   nullptr, nullptr, nullptr, nullptr);
  }

  // proj: out = Z @ Wp^T (8192 x 2304, K=2304), split at col 1152 + bias — 32x18=576 WGs
  {
    float* out0 = (float*)d_out;
    float* out1 = out0 + 9437184;
    gemmRP<2, 4><<<dim3(576), 512, 0, stream>>>(Z, 2304, 0, Wpb, 2304, 0, nullptr, 0, 0,
                                                2304, 1.0f, 18, 0,
                                                out0, out1, bproj_pix, bproj_text);
  }
}